// Round 6
// baseline (1831.893 us; speedup 1.0000x reference)
//
#include <hip/hip_runtime.h>

#define M_CODES 512
#define D_EMB 128
#define D4 32  // D_EMB / 4
// np-f32 golden rounds (sumE+sx) and the -2dot subtract at magnitude ~128:
// per-code perturbation up to ~1.53e-5; two codes can flip for gaps < ~3.1e-5.
#define MARGIN 5e-5f

__device__ __forceinline__ float dot4f(float4 a, float4 b, float acc) {
    acc = fmaf(a.x, b.x, acc);
    acc = fmaf(a.y, b.y, acc);
    acc = fmaf(a.z, b.z, acc);
    acc = fmaf(a.w, b.w, acc);
    return acc;
}

// numpy pairwise sum (n=128 <= PW_BLOCKSIZE): 8 strided accumulators + tree.
// Non-contractible _rn ops so codegen can't fuse mul+add into fma.
__device__ __forceinline__ float np_pairwise_sumsq128(const float* __restrict__ a,
                                                      float scale) {
    float r[8];
#pragma unroll
    for (int j = 0; j < 8; ++j) {
        float v = __fmul_rn(a[j], scale);
        r[j] = __fmul_rn(v, v);
    }
    for (int i = 8; i < 128; i += 8) {
#pragma unroll
        for (int j = 0; j < 8; ++j) {
            float v = __fmul_rn(a[i + j], scale);
            r[j] = __fadd_rn(r[j], __fmul_rn(v, v));
        }
    }
    return __fadd_rn(__fadd_rn(__fadd_rn(r[0], r[1]), __fadd_rn(r[2], r[3])),
                     __fadd_rn(__fadd_rn(r[4], r[5]), __fadd_rn(r[6], r[7])));
}

// Kernel S: sumE_np[m] = np-f32 pairwise sum of embedding[m]^2; zero flagCnt.
__global__ void kS(const float* __restrict__ emb, float* __restrict__ sumE,
                   int* __restrict__ flagCnt) {
    int m = blockIdx.x * 256 + threadIdx.x;
    if (m == 0 && blockIdx.x == 0) *flagCnt = 0;
    if (m < M_CODES) {
        sumE[m] = np_pairwise_sumsq128(emb + (size_t)m * D_EMB, 1.0f);
    }
}

// Kernel A: fast f32 screen for argmin; flags tokens whose top-2 gap is under
// MARGIN (where np-f32 rounding could order codes differently).
__global__ __launch_bounds__(256) void kA(const float* __restrict__ x,
                                          const float* __restrict__ xmask,
                                          const float* __restrict__ emb,
                                          const float* __restrict__ sumE,
                                          int* __restrict__ idx_out,
                                          int* __restrict__ flagCnt,
                                          int* __restrict__ flagList,
                                          float* __restrict__ lossP,
                                          float* __restrict__ maskP, int n) {
    int t = blockIdx.x * 256 + threadIdx.x;
    float mk = 0.f;
    float b1 = 3.4e38f, b2 = 3.4e38f;
    int bidx = 0;
    float xnorm = 0.f;
    float li = 0.f;
    if (t < n) {
        mk = xmask[t];
        float4 rx[D4];
        const float4* xr = reinterpret_cast<const float4*>(x + (size_t)t * D_EMB);
#pragma unroll
        for (int i = 0; i < D4; ++i) {
            float4 v = xr[i];
            v.x *= mk; v.y *= mk; v.z *= mk; v.w *= mk;
            rx[i] = v;
            xnorm = dot4f(v, v, xnorm);
        }
        const float4* E4 = reinterpret_cast<const float4*>(emb);
        for (int m0 = 0; m0 < M_CODES; m0 += 4) {
            float a0 = 0.f, a1 = 0.f, a2 = 0.f, a3 = 0.f;
            const float4* e0 = E4 + (size_t)m0 * D4;
            const float4* e1 = e0 + D4;
            const float4* e2 = e0 + 2 * D4;
            const float4* e3 = e0 + 3 * D4;
#pragma unroll
            for (int i = 0; i < D4; ++i) {
                float4 xv = rx[i];
                a0 = dot4f(xv, e0[i], a0);
                a1 = dot4f(xv, e1[i], a1);
                a2 = dot4f(xv, e2[i], a2);
                a3 = dot4f(xv, e3[i], a3);
            }
            float s0 = sumE[m0 + 0] - 2.f * a0;
            float s1 = sumE[m0 + 1] - 2.f * a1;
            float s2 = sumE[m0 + 2] - 2.f * a2;
            float s3 = sumE[m0 + 3] - 2.f * a3;
            if (s0 < b1) { b2 = b1; b1 = s0; bidx = m0 + 0; } else if (s0 < b2) b2 = s0;
            if (s1 < b1) { b2 = b1; b1 = s1; bidx = m0 + 1; } else if (s1 < b2) b2 = s1;
            if (s2 < b1) { b2 = b1; b1 = s2; bidx = m0 + 2; } else if (s2 < b2) b2 = s2;
            if (s3 < b1) { b2 = b1; b1 = s3; bidx = m0 + 3; } else if (s3 < b2) b2 = s3;
        }
        idx_out[t] = bidx;
        if (b2 - b1 < MARGIN) {
            int p = atomicAdd(flagCnt, 1);
            flagList[p] = t;
        }
        li = mk * mk * (xnorm + b1);
    }
    __shared__ float sred[256];
    sred[threadIdx.x] = li;
    __syncthreads();
#pragma unroll
    for (int s = 128; s > 0; s >>= 1) {
        if (threadIdx.x < s) sred[threadIdx.x] += sred[threadIdx.x + s];
        __syncthreads();
    }
    if (threadIdx.x == 0) lossP[blockIdx.x] = sred[0];
    __syncthreads();
    sred[threadIdx.x] = mk;
    __syncthreads();
#pragma unroll
    for (int s = 128; s > 0; s >>= 1) {
        if (threadIdx.x < s) sred[threadIdx.x] += sred[threadIdx.x + s];
        __syncthreads();
    }
    if (threadIdx.x == 0) maskP[blockIdx.x] = sred[0];
}

// Kernel F: bit-exact numpy-f32 pipeline for flagged tokens.
//   sx   = numpy pairwise-8 sum of (x*mk)^2            (f32)
//   dot  = BLAS-style sequential FMA chain over k=0..127 (f32, init 0)
//   d    = f32( f32(sumE_np + sx) - f32(2*dot) )
//   argmin with lowest-index tie-break.
__global__ __launch_bounds__(256) void kF(const float* __restrict__ x,
                                          const float* __restrict__ xmask,
                                          const float* __restrict__ emb,
                                          const float* __restrict__ sumE,
                                          const int* __restrict__ flagCnt,
                                          const int* __restrict__ flagList,
                                          int* __restrict__ idx_out) {
    int wave = (blockIdx.x * 256 + threadIdx.x) >> 6;
    int lane = threadIdx.x & 63;
    int nWaves = gridDim.x * 4;
    int cnt = *flagCnt;
    for (int j = wave; j < cnt; j += nWaves) {
        int t = flagList[j];
        float mk = xmask[t];
        const float* xr = x + (size_t)t * D_EMB;
        float sx = np_pairwise_sumsq128(xr, mk);
        float acc[8];
#pragma unroll
        for (int k = 0; k < 8; ++k) acc[k] = 0.f;
        for (int i = 0; i < D_EMB; ++i) {
            float xi = __fmul_rn(xr[i], mk);
#pragma unroll
            for (int k = 0; k < 8; ++k) {
                float ed = emb[(size_t)(k * 64 + lane) * D_EMB + i];
                acc[k] = __fmaf_rn(xi, ed, acc[k]);
            }
        }
        float best = 3.4e38f;
        int bidx = 0x7fffffff;
#pragma unroll
        for (int k = 0; k < 8; ++k) {
            int m = k * 64 + lane;
            float d = __fsub_rn(__fadd_rn(sumE[m], sx), __fmul_rn(2.f, acc[k]));
            if (d < best || (d == best && m < bidx)) { best = d; bidx = m; }
        }
#pragma unroll
        for (int off = 32; off > 0; off >>= 1) {
            float s2 = __shfl_xor(best, off, 64);
            int i2 = __shfl_xor(bidx, off, 64);
            if (s2 < best || (s2 == best && i2 < bidx)) { best = s2; bidx = i2; }
        }
        if (lane == 0) idx_out[t] = bidx;
    }
}

// Kernel Q: q_st = embedding[idx] * mask, coalesced writes (32 lanes per token).
__global__ void kQ(const float* __restrict__ emb, const float* __restrict__ xmask,
                   const int* __restrict__ idx, float* __restrict__ q_st, int n) {
    int g = blockIdx.x * 256 + threadIdx.x;
    int token = g >> 5;
    int d4 = g & 31;
    if (token < n) {
        int id = idx[token];
        float mk = xmask[token];
        const float4* E4 = reinterpret_cast<const float4*>(emb);
        float4 ev = E4[(size_t)id * D4 + d4];
        float4 o;
        o.x = ev.x * mk; o.y = ev.y * mk; o.z = ev.z * mk; o.w = ev.w * mk;
        reinterpret_cast<float4*>(q_st)[(size_t)token * D4 + d4] = o;
    }
}

// Kernel B: one block per code; scan indices, accumulate dw + count in LDS.
__global__ __launch_bounds__(256) void kB(const float* __restrict__ x,
                                          const float* __restrict__ xmask,
                                          const int* __restrict__ idx,
                                          const float* __restrict__ ema_w,
                                          float* __restrict__ new_w,
                                          float* __restrict__ counts, int n) {
    __shared__ float acc[D_EMB];
    __shared__ int cnt;
    int m = blockIdx.x;
    if (threadIdx.x < D_EMB) acc[threadIdx.x] = 0.f;
    if (threadIdx.x == 0) cnt = 0;
    __syncthreads();
    for (int t = threadIdx.x; t < n; t += 256) {
        if (idx[t] == m) {
            atomicAdd(&cnt, 1);
            float mk = xmask[t];
            const float4* xr = reinterpret_cast<const float4*>(x + (size_t)t * D_EMB);
#pragma unroll
            for (int i = 0; i < D4; ++i) {
                float4 v = xr[i];
                atomicAdd(&acc[4 * i + 0], v.x * mk);
                atomicAdd(&acc[4 * i + 1], v.y * mk);
                atomicAdd(&acc[4 * i + 2], v.z * mk);
                atomicAdd(&acc[4 * i + 3], v.w * mk);
            }
        }
    }
    __syncthreads();
    if (threadIdx.x < D_EMB) {
        float dw = acc[threadIdx.x];
        size_t o = (size_t)m * D_EMB + threadIdx.x;
        new_w[o] = 0.999f * ema_w[o] + 0.001f * dw;
    }
    if (threadIdx.x == 0) counts[m] = (float)cnt;
}

// Kernel C: count normalization + loss finalize.
__global__ __launch_bounds__(512) void kC(const float* __restrict__ counts,
                                          const float* __restrict__ ema_count,
                                          float* __restrict__ new_count_out,
                                          float* __restrict__ norm_ws,
                                          const float* __restrict__ lossP,
                                          const float* __restrict__ maskP,
                                          float* __restrict__ loss_out, int nP) {
    __shared__ float red[512];
    int t = threadIdx.x;
    float raw = 0.999f * ema_count[t] + 0.001f * counts[t];
    red[t] = raw;
    __syncthreads();
#pragma unroll
    for (int s = 256; s > 0; s >>= 1) {
        if (t < s) red[t] += red[t + s];
        __syncthreads();
    }
    float nsum = red[0];
    __syncthreads();
    float norm = (raw + 1e-5f) / (nsum + (float)M_CODES * 1e-5f) * nsum;
    new_count_out[t] = norm;
    norm_ws[t] = norm;

    float lp = 0.f, mp = 0.f;
    for (int i = t; i < nP; i += 512) { lp += lossP[i]; mp += maskP[i]; }
    red[t] = lp;
    __syncthreads();
#pragma unroll
    for (int s = 256; s > 0; s >>= 1) {
        if (t < s) red[t] += red[t + s];
        __syncthreads();
    }
    float S = red[0];
    __syncthreads();
    red[t] = mp;
    __syncthreads();
#pragma unroll
    for (int s = 256; s > 0; s >>= 1) {
        if (t < s) red[t] += red[t + s];
        __syncthreads();
    }
    if (t == 0) loss_out[0] = 0.25f * S / (red[0] * (float)D_EMB);
}

// Kernel D: new_embedding = new_weight / norm_count
__global__ void kD(const float* __restrict__ new_w, const float* __restrict__ norm_ws,
                   float* __restrict__ new_emb) {
    int i = blockIdx.x * 256 + threadIdx.x;
    new_emb[i] = new_w[i] / norm_ws[i >> 7];
}

extern "C" void kernel_launch(void* const* d_in, const int* in_sizes, int n_in,
                              void* d_out, int out_size, void* d_ws, size_t ws_size,
                              hipStream_t stream) {
    const float* x = (const float*)d_in[0];
    const float* xmask = (const float*)d_in[1];
    const float* emb = (const float*)d_in[2];
    const float* ema_count = (const float*)d_in[3];
    const float* ema_weight = (const float*)d_in[4];
    int N = in_sizes[0] / D_EMB;

    float* out = (float*)d_out;
    float* q_st = out;
    float* loss = out + (size_t)N * D_EMB;
    float* new_emb = loss + 1;
    float* new_cnt = new_emb + M_CODES * D_EMB;
    float* new_w = new_cnt + M_CODES;

    char* ws = (char*)d_ws;
    int gridA = (N + 255) / 256;
    int* idx = (int*)ws;                                   // N ints
    float* counts = (float*)(ws + (size_t)N * 4);          // 512
    float* norm = counts + M_CODES;                        // 512
    float* lossP = norm + M_CODES;                         // gridA
    float* maskP = lossP + gridA;                          // gridA
    float* sumE = maskP + gridA;                           // 512
    int* flagCnt = (int*)(sumE + M_CODES);                 // 1 (+pad)
    int* flagList = flagCnt + 2;                           // up to N ints

    hipLaunchKernelGGL(kS, dim3(2), dim3(256), 0, stream, emb, sumE, flagCnt);
    hipLaunchKernelGGL(kA, dim3(gridA), dim3(256), 0, stream, x, xmask, emb, sumE,
                       idx, flagCnt, flagList, lossP, maskP, N);
    hipLaunchKernelGGL(kF, dim3(128), dim3(256), 0, stream, x, xmask, emb, sumE,
                       flagCnt, flagList, idx);
    hipLaunchKernelGGL(kQ, dim3((N * D4 + 255) / 256), dim3(256), 0, stream, emb,
                       xmask, idx, q_st, N);
    hipLaunchKernelGGL(kB, dim3(M_CODES), dim3(256), 0, stream, x, xmask, idx,
                       ema_weight, new_w, counts, N);
    hipLaunchKernelGGL(kC, dim3(1), dim3(512), 0, stream, counts, ema_count,
                       new_cnt, norm, lossP, maskP, loss, gridA);
    hipLaunchKernelGGL(kD, dim3(M_CODES * D_EMB / 256), dim3(256), 0, stream,
                       new_w, norm, new_emb);
}

// Round 7
// 1151.284 us; speedup vs baseline: 1.5912x; 1.5912x over previous
//
#include <hip/hip_runtime.h>

#define M_CODES 512
#define D_EMB 128
#define D4 32       // D_EMB/4
#define MARGIN 5e-5f
#define NSUB 4      // code subsets
#define CPS 128     // codes per subset = M_CODES/NSUB

// numpy pairwise sum (n=128): 8 strided accumulators + tree. Non-contractible
// _rn ops so codegen can't fuse mul+add into fma. (R6-validated bit-exact.)
__device__ __forceinline__ float np_pairwise_sumsq128(const float* __restrict__ a,
                                                      float scale) {
    float r[8];
#pragma unroll
    for (int j = 0; j < 8; ++j) {
        float v = __fmul_rn(a[j], scale);
        r[j] = __fmul_rn(v, v);
    }
    for (int i = 8; i < 128; i += 8) {
#pragma unroll
        for (int j = 0; j < 8; ++j) {
            float v = __fmul_rn(a[i + j], scale);
            r[j] = __fadd_rn(r[j], __fmul_rn(v, v));
        }
    }
    return __fadd_rn(__fadd_rn(__fadd_rn(r[0], r[1]), __fadd_rn(r[2], r[3])),
                     __fadd_rn(__fadd_rn(r[4], r[5]), __fadd_rn(r[6], r[7])));
}

// kS: sumE_np[m] (np pairwise), embT[d][m] transpose for coalesced kF, zero flagCnt.
__global__ void kS(const float* __restrict__ emb, float* __restrict__ sumE,
                   float* __restrict__ embT, int* __restrict__ flagCnt) {
    int m = blockIdx.x * 256 + threadIdx.x;
    if (m == 0) *flagCnt = 0;
    if (m < M_CODES) {
        sumE[m] = np_pairwise_sumsq128(emb + (size_t)m * D_EMB, 1.0f);
        const float* er = emb + (size_t)m * D_EMB;
        for (int i = 0; i < D_EMB; ++i) embT[i * M_CODES + m] = er[i];
    }
}

// kA: split-K screen. Wave = 64 tokens x one 128-code subset. Code loads are
// wave-uniform (scalar-load path); x row lives in 32 float4 VGPRs.
__global__ __launch_bounds__(256) void kA(const float* __restrict__ x,
                                          const float* __restrict__ xmask,
                                          const float* __restrict__ emb,
                                          const float* __restrict__ sumE,
                                          float* __restrict__ pb1,
                                          float* __restrict__ pb2,
                                          int* __restrict__ pidx,
                                          float* __restrict__ xnrm, int N) {
    int lane = threadIdx.x & 63;
    int wib = __builtin_amdgcn_readfirstlane(threadIdx.x >> 6);
    int gw = blockIdx.x * 4 + wib;
    int sub = gw & (NSUB - 1);   // wave-uniform subset
    int tg = gw >> 2;
    int t = tg * 64 + lane;
    if (t >= N) return;
    float mk = xmask[t];
    float4 rx[D4];
    const float4* xr = reinterpret_cast<const float4*>(x + (size_t)t * D_EMB);
    float n0 = 0.f, n1 = 0.f, n2 = 0.f, n3 = 0.f;
#pragma unroll
    for (int i = 0; i < D4; ++i) {
        float4 v = xr[i];
        v.x *= mk; v.y *= mk; v.z *= mk; v.w *= mk;
        rx[i] = v;
        n0 = fmaf(v.x, v.x, n0); n1 = fmaf(v.y, v.y, n1);
        n2 = fmaf(v.z, v.z, n2); n3 = fmaf(v.w, v.w, n3);
    }
    if (sub == 0) xnrm[t] = (n0 + n1) + (n2 + n3);
    const float4* eb = reinterpret_cast<const float4*>(emb + (size_t)sub * CPS * D_EMB);
    const float* se = sumE + sub * CPS;
    float b1 = 3.4e38f, b2 = 3.4e38f;
    int bi = 0;
    for (int c = 0; c < CPS; ++c) {
        const float4* er = eb + (size_t)c * D4;
        float a0 = 0.f, a1 = 0.f, a2 = 0.f, a3 = 0.f;
#pragma unroll
        for (int i = 0; i < D4; ++i) {
            float4 e = er[i], v = rx[i];
            a0 = fmaf(v.x, e.x, a0); a1 = fmaf(v.y, e.y, a1);
            a2 = fmaf(v.z, e.z, a2); a3 = fmaf(v.w, e.w, a3);
        }
        float s = fmaf(-2.f, (a0 + a1) + (a2 + a3), se[c]);
        if (s < b1) { b2 = b1; b1 = s; bi = sub * CPS + c; } else if (s < b2) b2 = s;
    }
    size_t o = (size_t)sub * N + t;
    pb1[o] = b1; pb2[o] = b2; pidx[o] = bi;
}

// kA2: merge subset partials -> global argmin, flag near-ties, loss partials.
__global__ __launch_bounds__(256) void kA2(const float* __restrict__ pb1,
                                           const float* __restrict__ pb2,
                                           const int* __restrict__ pidx,
                                           const float* __restrict__ xnrm,
                                           const float* __restrict__ xmask,
                                           int* __restrict__ idx_out,
                                           int* __restrict__ flagCnt,
                                           int* __restrict__ flagList,
                                           float* __restrict__ lossP,
                                           float* __restrict__ maskP, int N) {
    int t = blockIdx.x * 256 + threadIdx.x;
    float mk = 0.f, li = 0.f;
    if (t < N) {
        mk = xmask[t];
        float b1 = 3.4e38f, b2 = 3.4e38f;
        int bi = 0;
#pragma unroll
        for (int s = 0; s < NSUB; ++s) {
            size_t o = (size_t)s * N + t;
            float v1 = pb1[o], v2 = pb2[o];
            int vi = pidx[o];
            if (v1 < b1) { b2 = fminf(b1, v2); b1 = v1; bi = vi; }
            else b2 = fminf(b2, v1);  // ties (v1==b1) -> b2<=b1 -> flagged
        }
        idx_out[t] = bi;
        if (b2 - b1 < MARGIN) {
            int p = atomicAdd(flagCnt, 1);
            flagList[p] = t;
        }
        li = mk * mk * (xnrm[t] + b1);
    }
    __shared__ float sred[256];
    sred[threadIdx.x] = li;
    __syncthreads();
#pragma unroll
    for (int s = 128; s > 0; s >>= 1) {
        if (threadIdx.x < s) sred[threadIdx.x] += sred[threadIdx.x + s];
        __syncthreads();
    }
    if (threadIdx.x == 0) lossP[blockIdx.x] = sred[0];
    __syncthreads();
    sred[threadIdx.x] = mk;
    __syncthreads();
#pragma unroll
    for (int s = 128; s > 0; s >>= 1) {
        if (threadIdx.x < s) sred[threadIdx.x] += sred[threadIdx.x + s];
        __syncthreads();
    }
    if (threadIdx.x == 0) maskP[blockIdx.x] = sred[0];
}

// kF: bit-exact np-f32 full rescan for flagged tokens, one wave/token.
// Lane = code within 64-code chunk; embT makes the per-i loads coalesced.
// Sequential __fmaf_rn chain over i per (t,c) == np golden (R6-validated).
__global__ __launch_bounds__(256) void kF(const float* __restrict__ x,
                                          const float* __restrict__ xmask,
                                          const float* __restrict__ embT,
                                          const float* __restrict__ sumE,
                                          const int* __restrict__ flagCnt,
                                          const int* __restrict__ flagList,
                                          int* __restrict__ idx_out) {
    int wave = (blockIdx.x * 256 + threadIdx.x) >> 6;
    int lane = threadIdx.x & 63;
    int nW = gridDim.x * 4;
    int cnt = *flagCnt;
    for (int j = wave; j < cnt; j += nW) {
        int t = flagList[j];
        float mk = xmask[t];
        const float* xr = x + (size_t)t * D_EMB;
        float sx = np_pairwise_sumsq128(xr, mk);
        float best = 3.4e38f;
        int bi = 0x7fffffff;
        for (int cb = 0; cb < 8; ++cb) {
            int c = cb * 64 + lane;
            float acc = 0.f;
            for (int i = 0; i < D_EMB; ++i) {
                float xi = __fmul_rn(xr[i], mk);
                acc = __fmaf_rn(xi, embT[i * M_CODES + c], acc);
            }
            float d = __fsub_rn(__fadd_rn(sumE[c], sx), __fmul_rn(2.f, acc));
            if (d < best || (d == best && c < bi)) { best = d; bi = c; }
        }
#pragma unroll
        for (int off = 32; off > 0; off >>= 1) {
            float s2 = __shfl_xor(best, off, 64);
            int i2 = __shfl_xor(bi, off, 64);
            if (s2 < best || (s2 == best && i2 < bi)) { best = s2; bi = i2; }
        }
        if (lane == 0) idx_out[t] = bi;
    }
}

// kQ: q_st = embedding[idx] * mask, coalesced (32 lanes per token).
__global__ void kQ(const float* __restrict__ emb, const float* __restrict__ xmask,
                   const int* __restrict__ idx, float* __restrict__ q_st, int n) {
    int g = blockIdx.x * 256 + threadIdx.x;
    int token = g >> 5;
    int d4 = g & 31;
    if (token < n) {
        int id = idx[token];
        float mk = xmask[token];
        const float4* E4 = reinterpret_cast<const float4*>(emb);
        float4 ev = E4[(size_t)id * D4 + d4];
        float4 o;
        o.x = ev.x * mk; o.y = ev.y * mk; o.z = ev.z * mk; o.w = ev.w * mk;
        reinterpret_cast<float4*>(q_st)[(size_t)token * D4 + d4] = o;
    }
}

// kB: one block per code; scan indices, accumulate dw + count in LDS.
__global__ __launch_bounds__(256) void kB(const float* __restrict__ x,
                                          const float* __restrict__ xmask,
                                          const int* __restrict__ idx,
                                          const float* __restrict__ ema_w,
                                          float* __restrict__ new_w,
                                          float* __restrict__ counts, int n) {
    __shared__ float acc[D_EMB];
    __shared__ int cnt;
    int m = blockIdx.x;
    if (threadIdx.x < D_EMB) acc[threadIdx.x] = 0.f;
    if (threadIdx.x == 0) cnt = 0;
    __syncthreads();
    for (int t = threadIdx.x; t < n; t += 256) {
        if (idx[t] == m) {
            atomicAdd(&cnt, 1);
            float mk = xmask[t];
            const float4* xr = reinterpret_cast<const float4*>(x + (size_t)t * D_EMB);
#pragma unroll
            for (int i = 0; i < D4; ++i) {
                float4 v = xr[i];
                atomicAdd(&acc[4 * i + 0], v.x * mk);
                atomicAdd(&acc[4 * i + 1], v.y * mk);
                atomicAdd(&acc[4 * i + 2], v.z * mk);
                atomicAdd(&acc[4 * i + 3], v.w * mk);
            }
        }
    }
    __syncthreads();
    if (threadIdx.x < D_EMB) {
        float dw = acc[threadIdx.x];
        size_t o = (size_t)m * D_EMB + threadIdx.x;
        new_w[o] = 0.999f * ema_w[o] + 0.001f * dw;
    }
    if (threadIdx.x == 0) counts[m] = (float)cnt;
}

// kC: count normalization + loss finalize.
__global__ __launch_bounds__(512) void kC(const float* __restrict__ counts,
                                          const float* __restrict__ ema_count,
                                          float* __restrict__ new_count_out,
                                          float* __restrict__ norm_ws,
                                          const float* __restrict__ lossP,
                                          const float* __restrict__ maskP,
                                          float* __restrict__ loss_out, int nP) {
    __shared__ float red[512];
    int t = threadIdx.x;
    float raw = 0.999f * ema_count[t] + 0.001f * counts[t];
    red[t] = raw;
    __syncthreads();
#pragma unroll
    for (int s = 256; s > 0; s >>= 1) {
        if (t < s) red[t] += red[t + s];
        __syncthreads();
    }
    float nsum = red[0];
    __syncthreads();
    float norm = (raw + 1e-5f) / (nsum + (float)M_CODES * 1e-5f) * nsum;
    new_count_out[t] = norm;
    norm_ws[t] = norm;

    float lp = 0.f, mp = 0.f;
    for (int i = t; i < nP; i += 512) { lp += lossP[i]; mp += maskP[i]; }
    red[t] = lp;
    __syncthreads();
#pragma unroll
    for (int s = 256; s > 0; s >>= 1) {
        if (t < s) red[t] += red[t + s];
        __syncthreads();
    }
    float S = red[0];
    __syncthreads();
    red[t] = mp;
    __syncthreads();
#pragma unroll
    for (int s = 256; s > 0; s >>= 1) {
        if (t < s) red[t] += red[t + s];
        __syncthreads();
    }
    if (t == 0) loss_out[0] = 0.25f * S / (red[0] * (float)D_EMB);
}

// kD: new_embedding = new_weight / norm_count
__global__ void kD(const float* __restrict__ new_w, const float* __restrict__ norm_ws,
                   float* __restrict__ new_emb) {
    int i = blockIdx.x * 256 + threadIdx.x;
    new_emb[i] = new_w[i] / norm_ws[i >> 7];
}

extern "C" void kernel_launch(void* const* d_in, const int* in_sizes, int n_in,
                              void* d_out, int out_size, void* d_ws, size_t ws_size,
                              hipStream_t stream) {
    const float* x = (const float*)d_in[0];
    const float* xmask = (const float*)d_in[1];
    const float* emb = (const float*)d_in[2];
    const float* ema_count = (const float*)d_in[3];
    const float* ema_weight = (const float*)d_in[4];
    int N = in_sizes[0] / D_EMB;

    float* out = (float*)d_out;
    float* q_st = out;
    float* loss = out + (size_t)N * D_EMB;
    float* new_emb = loss + 1;
    float* new_cnt = new_emb + M_CODES * D_EMB;
    float* new_w = new_cnt + M_CODES;

    char* ws = (char*)d_ws;
    int gridA2 = (N + 255) / 256;  // 256
    float* fws = (float*)ws;
    int* idx = (int*)fws;                     // N
    float* counts = fws + N;                  // 512
    float* norm = counts + M_CODES;           // 512
    float* lossP = norm + M_CODES;            // gridA2
    float* maskP = lossP + gridA2;            // gridA2
    float* sumE = maskP + gridA2;             // 512
    int* flagCnt = (int*)(sumE + M_CODES);    // 2
    int* flagList = flagCnt + 2;              // N
    float* xnrm = (float*)(flagList + N);     // N
    float* pb1 = xnrm + N;                    // NSUB*N
    float* pb2 = pb1 + (size_t)NSUB * N;      // NSUB*N
    int* pidx = (int*)(pb2 + (size_t)NSUB * N); // NSUB*N
    float* embT = (float*)(pidx + (size_t)NSUB * N); // 65536

    int wavesA = NSUB * (N / 64);             // 4096
    hipLaunchKernelGGL(kS, dim3(2), dim3(256), 0, stream, emb, sumE, embT, flagCnt);
    hipLaunchKernelGGL(kA, dim3(wavesA / 4), dim3(256), 0, stream, x, xmask, emb,
                       sumE, pb1, pb2, pidx, xnrm, N);
    hipLaunchKernelGGL(kA2, dim3(gridA2), dim3(256), 0, stream, pb1, pb2, pidx,
                       xnrm, xmask, idx, flagCnt, flagList, lossP, maskP, N);
    hipLaunchKernelGGL(kF, dim3(512), dim3(256), 0, stream, x, xmask, embT, sumE,
                       flagCnt, flagList, idx);
    hipLaunchKernelGGL(kQ, dim3((N * D4 + 255) / 256), dim3(256), 0, stream, emb,
                       xmask, idx, q_st, N);
    hipLaunchKernelGGL(kB, dim3(M_CODES), dim3(256), 0, stream, x, xmask, idx,
                       ema_weight, new_w, counts, N);
    hipLaunchKernelGGL(kC, dim3(1), dim3(512), 0, stream, counts, ema_count,
                       new_cnt, norm, lossP, maskP, loss, gridA2);
    hipLaunchKernelGGL(kD, dim3(M_CODES * D_EMB / 256), dim3(256), 0, stream,
                       new_w, norm, new_emb);
}

// Round 8
// 514.215 us; speedup vs baseline: 3.5625x; 2.2389x over previous
//
#include <hip/hip_runtime.h>

#define M_CODES 512
#define D_EMB 128
#define D4 32       // D_EMB/4
#define MARGIN 5e-5f
#define NSUB 4      // code subsets
#define CPS 128     // codes per subset = M_CODES/NSUB

// numpy pairwise sum (n=128): 8 strided accumulators + tree. Non-contractible
// _rn ops so codegen can't fuse mul+add into fma. (R6-validated bit-exact.)
__device__ __forceinline__ float np_pairwise_sumsq128(const float* __restrict__ a,
                                                      float scale) {
    float r[8];
#pragma unroll
    for (int j = 0; j < 8; ++j) {
        float v = __fmul_rn(a[j], scale);
        r[j] = __fmul_rn(v, v);
    }
    for (int i = 8; i < 128; i += 8) {
#pragma unroll
        for (int j = 0; j < 8; ++j) {
            float v = __fmul_rn(a[i + j], scale);
            r[j] = __fadd_rn(r[j], __fmul_rn(v, v));
        }
    }
    return __fadd_rn(__fadd_rn(__fadd_rn(r[0], r[1]), __fadd_rn(r[2], r[3])),
                     __fadd_rn(__fadd_rn(r[4], r[5]), __fadd_rn(r[6], r[7])));
}

// kZ: zero the scatter accumulators (harness doesn't re-poison; we must re-zero
// every call for determinism). 512*128 weights + 512 counts + flagCnt.
__global__ void kZ(float* __restrict__ accw, float* __restrict__ accc,
                   int* __restrict__ flagCnt) {
    int i = blockIdx.x * 256 + threadIdx.x;
    accw[i] = 0.f;
    if (i < M_CODES) accc[i] = 0.f;
    if (i == 0) *flagCnt = 0;
}

// kS: sumE_np[m] (np pairwise) + embT[d][m] transpose for coalesced kF.
__global__ void kS(const float* __restrict__ emb, float* __restrict__ sumE,
                   float* __restrict__ embT) {
    int m = blockIdx.x * 256 + threadIdx.x;
    if (m < M_CODES) {
        sumE[m] = np_pairwise_sumsq128(emb + (size_t)m * D_EMB, 1.0f);
        const float* er = emb + (size_t)m * D_EMB;
        for (int i = 0; i < D_EMB; ++i) embT[i * M_CODES + m] = er[i];
    }
}

// kA: split-K screen. Wave = 64 tokens x one 128-code subset. Code loads are
// wave-uniform (scalar-load path); x row lives in 32 float4 VGPRs.
__global__ __launch_bounds__(256) void kA(const float* __restrict__ x,
                                          const float* __restrict__ xmask,
                                          const float* __restrict__ emb,
                                          const float* __restrict__ sumE,
                                          float* __restrict__ pb1,
                                          float* __restrict__ pb2,
                                          int* __restrict__ pidx,
                                          float* __restrict__ xnrm, int N) {
    int lane = threadIdx.x & 63;
    int wib = __builtin_amdgcn_readfirstlane(threadIdx.x >> 6);
    int gw = blockIdx.x * 4 + wib;
    int sub = gw & (NSUB - 1);   // wave-uniform subset
    int tg = gw >> 2;
    int t = tg * 64 + lane;
    if (t >= N) return;
    float mk = xmask[t];
    float4 rx[D4];
    const float4* xr = reinterpret_cast<const float4*>(x + (size_t)t * D_EMB);
    float n0 = 0.f, n1 = 0.f, n2 = 0.f, n3 = 0.f;
#pragma unroll
    for (int i = 0; i < D4; ++i) {
        float4 v = xr[i];
        v.x *= mk; v.y *= mk; v.z *= mk; v.w *= mk;
        rx[i] = v;
        n0 = fmaf(v.x, v.x, n0); n1 = fmaf(v.y, v.y, n1);
        n2 = fmaf(v.z, v.z, n2); n3 = fmaf(v.w, v.w, n3);
    }
    if (sub == 0) xnrm[t] = (n0 + n1) + (n2 + n3);
    const float4* eb = reinterpret_cast<const float4*>(emb + (size_t)sub * CPS * D_EMB);
    const float* se = sumE + sub * CPS;
    float b1 = 3.4e38f, b2 = 3.4e38f;
    int bi = 0;
    for (int c = 0; c < CPS; ++c) {
        const float4* er = eb + (size_t)c * D4;
        float a0 = 0.f, a1 = 0.f, a2 = 0.f, a3 = 0.f;
#pragma unroll
        for (int i = 0; i < D4; ++i) {
            float4 e = er[i], v = rx[i];
            a0 = fmaf(v.x, e.x, a0); a1 = fmaf(v.y, e.y, a1);
            a2 = fmaf(v.z, e.z, a2); a3 = fmaf(v.w, e.w, a3);
        }
        float s = fmaf(-2.f, (a0 + a1) + (a2 + a3), se[c]);
        if (s < b1) { b2 = b1; b1 = s; bi = sub * CPS + c; } else if (s < b2) b2 = s;
    }
    size_t o = (size_t)sub * N + t;
    pb1[o] = b1; pb2[o] = b2; pidx[o] = bi;
}

// kA2: merge subset partials -> global argmin, flag near-ties, loss partials.
__global__ __launch_bounds__(256) void kA2(const float* __restrict__ pb1,
                                           const float* __restrict__ pb2,
                                           const int* __restrict__ pidx,
                                           const float* __restrict__ xnrm,
                                           const float* __restrict__ xmask,
                                           int* __restrict__ idx_out,
                                           int* __restrict__ flagCnt,
                                           int* __restrict__ flagList,
                                           float* __restrict__ lossP,
                                           float* __restrict__ maskP, int N) {
    int t = blockIdx.x * 256 + threadIdx.x;
    float mk = 0.f, li = 0.f;
    if (t < N) {
        mk = xmask[t];
        float b1 = 3.4e38f, b2 = 3.4e38f;
        int bi = 0;
#pragma unroll
        for (int s = 0; s < NSUB; ++s) {
            size_t o = (size_t)s * N + t;
            float v1 = pb1[o], v2 = pb2[o];
            int vi = pidx[o];
            if (v1 < b1) { b2 = fminf(b1, v2); b1 = v1; bi = vi; }
            else b2 = fminf(b2, v1);  // ties (v1==b1) -> b2<=b1 -> flagged
        }
        idx_out[t] = bi;
        if (b2 - b1 < MARGIN) {
            int p = atomicAdd(flagCnt, 1);
            flagList[p] = t;
        }
        li = mk * mk * (xnrm[t] + b1);
    }
    __shared__ float sred[256];
    sred[threadIdx.x] = li;
    __syncthreads();
#pragma unroll
    for (int s = 128; s > 0; s >>= 1) {
        if (threadIdx.x < s) sred[threadIdx.x] += sred[threadIdx.x + s];
        __syncthreads();
    }
    if (threadIdx.x == 0) lossP[blockIdx.x] = sred[0];
    __syncthreads();
    sred[threadIdx.x] = mk;
    __syncthreads();
#pragma unroll
    for (int s = 128; s > 0; s >>= 1) {
        if (threadIdx.x < s) sred[threadIdx.x] += sred[threadIdx.x + s];
        __syncthreads();
    }
    if (threadIdx.x == 0) maskP[blockIdx.x] = sred[0];
}

// kF: bit-exact np-f32 full rescan for flagged tokens, one wave/token.
__global__ __launch_bounds__(256) void kF(const float* __restrict__ x,
                                          const float* __restrict__ xmask,
                                          const float* __restrict__ embT,
                                          const float* __restrict__ sumE,
                                          const int* __restrict__ flagCnt,
                                          const int* __restrict__ flagList,
                                          int* __restrict__ idx_out) {
    int wave = (blockIdx.x * 256 + threadIdx.x) >> 6;
    int lane = threadIdx.x & 63;
    int nW = gridDim.x * 4;
    int cnt = *flagCnt;
    for (int j = wave; j < cnt; j += nW) {
        int t = flagList[j];
        float mk = xmask[t];
        const float* xr = x + (size_t)t * D_EMB;
        float sx = np_pairwise_sumsq128(xr, mk);
        float best = 3.4e38f;
        int bi = 0x7fffffff;
        for (int cb = 0; cb < 8; ++cb) {
            int c = cb * 64 + lane;
            float acc = 0.f;
            for (int i = 0; i < D_EMB; ++i) {
                float xi = __fmul_rn(xr[i], mk);
                acc = __fmaf_rn(xi, embT[i * M_CODES + c], acc);
            }
            float d = __fsub_rn(__fadd_rn(sumE[c], sx), __fmul_rn(2.f, acc));
            if (d < best || (d == best && c < bi)) { best = d; bi = c; }
        }
#pragma unroll
        for (int off = 32; off > 0; off >>= 1) {
            float s2 = __shfl_xor(best, off, 64);
            int i2 = __shfl_xor(bi, off, 64);
            if (s2 < best || (s2 == best && i2 < bi)) { best = s2; bi = i2; }
        }
        if (lane == 0) idx_out[t] = bi;
    }
}

// kQ: q_st = embedding[idx] * mask, coalesced (32 lanes per token).
__global__ void kQ(const float* __restrict__ emb, const float* __restrict__ xmask,
                   const int* __restrict__ idx, float* __restrict__ q_st, int n) {
    int g = blockIdx.x * 256 + threadIdx.x;
    int token = g >> 5;
    int d4 = g & 31;
    if (token < n) {
        int id = idx[token];
        float mk = xmask[token];
        const float4* E4 = reinterpret_cast<const float4*>(emb);
        float4 ev = E4[(size_t)id * D4 + d4];
        float4 o;
        o.x = ev.x * mk; o.y = ev.y * mk; o.z = ev.z * mk; o.w = ev.w * mk;
        reinterpret_cast<float4*>(q_st)[(size_t)token * D4 + d4] = o;
    }
}

// kB2: token-parallel scatter. Thread = (token, d4): 4 global f32 atomics into
// accw[code][d]; lane d4==0 also bumps the count. 8.4M atomics over 65536
// addresses -> fully parallel across codes*dims, ~tens of us.
__global__ __launch_bounds__(256) void kB2(const float* __restrict__ x,
                                           const float* __restrict__ xmask,
                                           const int* __restrict__ idx,
                                           float* __restrict__ accw,
                                           float* __restrict__ accc, int N) {
    int g = blockIdx.x * 256 + threadIdx.x;
    int t = g >> 5;
    int d4 = g & 31;
    if (t < N) {
        int id = idx[t];
        float mk = xmask[t];
        float4 v = reinterpret_cast<const float4*>(x + (size_t)t * D_EMB)[d4];
        float* dst = accw + (size_t)id * D_EMB + d4 * 4;
        atomicAdd(dst + 0, v.x * mk);
        atomicAdd(dst + 1, v.y * mk);
        atomicAdd(dst + 2, v.z * mk);
        atomicAdd(dst + 3, v.w * mk);
        if (d4 == 0) atomicAdd(accc + id, 1.0f);
    }
}

// kC: count normalization + loss finalize.
__global__ __launch_bounds__(512) void kC(const float* __restrict__ counts,
                                          const float* __restrict__ ema_count,
                                          float* __restrict__ new_count_out,
                                          float* __restrict__ norm_ws,
                                          const float* __restrict__ lossP,
                                          const float* __restrict__ maskP,
                                          float* __restrict__ loss_out, int nP) {
    __shared__ float red[512];
    int t = threadIdx.x;
    float raw = 0.999f * ema_count[t] + 0.001f * counts[t];
    red[t] = raw;
    __syncthreads();
#pragma unroll
    for (int s = 256; s > 0; s >>= 1) {
        if (t < s) red[t] += red[t + s];
        __syncthreads();
    }
    float nsum = red[0];
    __syncthreads();
    float norm = (raw + 1e-5f) / (nsum + (float)M_CODES * 1e-5f) * nsum;
    new_count_out[t] = norm;
    norm_ws[t] = norm;

    float lp = 0.f, mp = 0.f;
    for (int i = t; i < nP; i += 512) { lp += lossP[i]; mp += maskP[i]; }
    red[t] = lp;
    __syncthreads();
#pragma unroll
    for (int s = 256; s > 0; s >>= 1) {
        if (t < s) red[t] += red[t + s];
        __syncthreads();
    }
    float S = red[0];
    __syncthreads();
    red[t] = mp;
    __syncthreads();
#pragma unroll
    for (int s = 256; s > 0; s >>= 1) {
        if (t < s) red[t] += red[t + s];
        __syncthreads();
    }
    if (t == 0) loss_out[0] = 0.25f * S / (red[0] * (float)D_EMB);
}

// kWD: new_w = 0.999*ema_w + 0.001*accw ; new_emb = new_w / norm[m]
__global__ void kWD(const float* __restrict__ accw, const float* __restrict__ ema_w,
                    const float* __restrict__ norm_ws, float* __restrict__ new_w,
                    float* __restrict__ new_emb) {
    int i = blockIdx.x * 256 + threadIdx.x;
    float w = 0.999f * ema_w[i] + 0.001f * accw[i];
    new_w[i] = w;
    new_emb[i] = w / norm_ws[i >> 7];
}

extern "C" void kernel_launch(void* const* d_in, const int* in_sizes, int n_in,
                              void* d_out, int out_size, void* d_ws, size_t ws_size,
                              hipStream_t stream) {
    const float* x = (const float*)d_in[0];
    const float* xmask = (const float*)d_in[1];
    const float* emb = (const float*)d_in[2];
    const float* ema_count = (const float*)d_in[3];
    const float* ema_weight = (const float*)d_in[4];
    int N = in_sizes[0] / D_EMB;

    float* out = (float*)d_out;
    float* q_st = out;
    float* loss = out + (size_t)N * D_EMB;
    float* new_emb = loss + 1;
    float* new_cnt = new_emb + M_CODES * D_EMB;
    float* new_w = new_cnt + M_CODES;

    char* ws = (char*)d_ws;
    int gridA2 = (N + 255) / 256;  // 256
    float* fws = (float*)ws;
    int* idx = (int*)fws;                     // N
    float* counts = fws + N;                  // 512 (accc)
    float* norm = counts + M_CODES;           // 512
    float* lossP = norm + M_CODES;            // gridA2
    float* maskP = lossP + gridA2;            // gridA2
    float* sumE = maskP + gridA2;             // 512
    int* flagCnt = (int*)(sumE + M_CODES);    // 2
    int* flagList = flagCnt + 2;              // N
    float* xnrm = (float*)(flagList + N);     // N
    float* pb1 = xnrm + N;                    // NSUB*N
    float* pb2 = pb1 + (size_t)NSUB * N;      // NSUB*N
    int* pidx = (int*)(pb2 + (size_t)NSUB * N); // NSUB*N
    float* embT = (float*)(pidx + (size_t)NSUB * N); // 65536
    float* accw = embT + M_CODES * D_EMB;     // 65536

    int wavesA = NSUB * (N / 64);             // 4096
    hipLaunchKernelGGL(kZ, dim3(M_CODES * D_EMB / 256), dim3(256), 0, stream,
                       accw, counts, flagCnt);
    hipLaunchKernelGGL(kS, dim3(2), dim3(256), 0, stream, emb, sumE, embT);
    hipLaunchKernelGGL(kA, dim3(wavesA / 4), dim3(256), 0, stream, x, xmask, emb,
                       sumE, pb1, pb2, pidx, xnrm, N);
    hipLaunchKernelGGL(kA2, dim3(gridA2), dim3(256), 0, stream, pb1, pb2, pidx,
                       xnrm, xmask, idx, flagCnt, flagList, lossP, maskP, N);
    hipLaunchKernelGGL(kF, dim3(512), dim3(256), 0, stream, x, xmask, embT, sumE,
                       flagCnt, flagList, idx);
    hipLaunchKernelGGL(kQ, dim3((N * D4 + 255) / 256), dim3(256), 0, stream, emb,
                       xmask, idx, q_st, N);
    hipLaunchKernelGGL(kB2, dim3((N * 32 + 255) / 256), dim3(256), 0, stream, x,
                       xmask, idx, accw, counts, N);
    hipLaunchKernelGGL(kC, dim3(1), dim3(512), 0, stream, counts, ema_count,
                       new_cnt, norm, lossP, maskP, loss, gridA2);
    hipLaunchKernelGGL(kWD, dim3(M_CODES * D_EMB / 256), dim3(256), 0, stream,
                       accw, ema_weight, norm, new_w, new_emb);
}

// Round 9
// 508.789 us; speedup vs baseline: 3.6005x; 1.0107x over previous
//
#include <hip/hip_runtime.h>

#define M_CODES 512
#define D_EMB 128
#define D4 32       // D_EMB/4
#define MARGIN 5e-5f
#define NSUB 4      // code subsets
#define CPS 128     // codes per subset = M_CODES/NSUB

// numpy pairwise sum (n=128): 8 strided accumulators + tree. Non-contractible
// _rn ops so codegen can't fuse mul+add into fma. (R6-validated bit-exact.)
__device__ __forceinline__ float np_pairwise_sumsq128(const float* __restrict__ a,
                                                      float scale) {
    float r[8];
#pragma unroll
    for (int j = 0; j < 8; ++j) {
        float v = __fmul_rn(a[j], scale);
        r[j] = __fmul_rn(v, v);
    }
    for (int i = 8; i < 128; i += 8) {
#pragma unroll
        for (int j = 0; j < 8; ++j) {
            float v = __fmul_rn(a[i + j], scale);
            r[j] = __fadd_rn(r[j], __fmul_rn(v, v));
        }
    }
    return __fadd_rn(__fadd_rn(__fadd_rn(r[0], r[1]), __fadd_rn(r[2], r[3])),
                     __fadd_rn(__fadd_rn(r[4], r[5]), __fadd_rn(r[6], r[7])));
}

// kSZ: fused setup — zero accw/accc/flagCnt (harness doesn't re-poison), and
// for m<512 compute sumE_np + embT transpose. Grid 256x256 covers accw 65536.
__global__ void kSZ(const float* __restrict__ emb, float* __restrict__ sumE,
                    float* __restrict__ embT, float* __restrict__ accw,
                    float* __restrict__ accc, int* __restrict__ flagCnt) {
    int i = blockIdx.x * 256 + threadIdx.x;
    accw[i] = 0.f;
    if (i < M_CODES) accc[i] = 0.f;
    if (i == 0) *flagCnt = 0;
    if (i < M_CODES) {
        sumE[i] = np_pairwise_sumsq128(emb + (size_t)i * D_EMB, 1.0f);
        const float* er = emb + (size_t)i * D_EMB;
        for (int d = 0; d < D_EMB; ++d) embT[d * M_CODES + i] = er[d];
    }
}

// kA: split-K screen. Wave = 64 tokens x one 128-code subset. Code loads are
// wave-uniform (scalar path); x row MUST stay in 32 float4 VGPRs -> allow max
// VGPR via min-waves=1 (R8: default bounds gave VGPR=100 < 128 needed; the
// compiler re-streamed x from L1 every code iteration -> VALUBusy 26%).
__global__ __launch_bounds__(256, 1) void kA(const float* __restrict__ x,
                                             const float* __restrict__ xmask,
                                             const float* __restrict__ emb,
                                             const float* __restrict__ sumE,
                                             float* __restrict__ pb1,
                                             float* __restrict__ pb2,
                                             int* __restrict__ pidx,
                                             float* __restrict__ xnrm, int N) {
    int lane = threadIdx.x & 63;
    int wib = __builtin_amdgcn_readfirstlane(threadIdx.x >> 6);
    int gw = blockIdx.x * 4 + wib;
    int sub = gw & (NSUB - 1);   // wave-uniform subset
    int tg = gw >> 2;
    int t = tg * 64 + lane;
    if (t >= N) return;
    float mk = xmask[t];
    float4 rx[D4];
    const float4* xr = reinterpret_cast<const float4*>(x + (size_t)t * D_EMB);
    float n0 = 0.f, n1 = 0.f, n2 = 0.f, n3 = 0.f;
#pragma unroll
    for (int i = 0; i < D4; ++i) {
        float4 v = xr[i];
        v.x *= mk; v.y *= mk; v.z *= mk; v.w *= mk;
        rx[i] = v;
        n0 = fmaf(v.x, v.x, n0); n1 = fmaf(v.y, v.y, n1);
        n2 = fmaf(v.z, v.z, n2); n3 = fmaf(v.w, v.w, n3);
    }
    if (sub == 0) xnrm[t] = (n0 + n1) + (n2 + n3);
    const float4* eb = reinterpret_cast<const float4*>(emb + (size_t)sub * CPS * D_EMB);
    const float* se = sumE + sub * CPS;
    float b1 = 3.4e38f, b2 = 3.4e38f;
    int bi = 0;
    for (int c = 0; c < CPS; ++c) {
        const float4* er = eb + (size_t)c * D4;
        float a0 = 0.f, a1 = 0.f, a2 = 0.f, a3 = 0.f;
#pragma unroll
        for (int i = 0; i < D4; ++i) {
            float4 e = er[i], v = rx[i];
            a0 = fmaf(v.x, e.x, a0); a1 = fmaf(v.y, e.y, a1);
            a2 = fmaf(v.z, e.z, a2); a3 = fmaf(v.w, e.w, a3);
        }
        float s = fmaf(-2.f, (a0 + a1) + (a2 + a3), se[c]);
        if (s < b1) { b2 = b1; b1 = s; bi = sub * CPS + c; } else if (s < b2) b2 = s;
    }
    size_t o = (size_t)sub * N + t;
    pb1[o] = b1; pb2[o] = b2; pidx[o] = bi;
}

// kA2: merge subset partials -> global argmin, flag near-ties, loss partials.
__global__ __launch_bounds__(256) void kA2(const float* __restrict__ pb1,
                                           const float* __restrict__ pb2,
                                           const int* __restrict__ pidx,
                                           const float* __restrict__ xnrm,
                                           const float* __restrict__ xmask,
                                           int* __restrict__ idx_out,
                                           int* __restrict__ flagCnt,
                                           int* __restrict__ flagList,
                                           float* __restrict__ lossP,
                                           float* __restrict__ maskP, int N) {
    int t = blockIdx.x * 256 + threadIdx.x;
    float mk = 0.f, li = 0.f;
    if (t < N) {
        mk = xmask[t];
        float b1 = 3.4e38f, b2 = 3.4e38f;
        int bi = 0;
#pragma unroll
        for (int s = 0; s < NSUB; ++s) {
            size_t o = (size_t)s * N + t;
            float v1 = pb1[o], v2 = pb2[o];
            int vi = pidx[o];
            if (v1 < b1) { b2 = fminf(b1, v2); b1 = v1; bi = vi; }
            else b2 = fminf(b2, v1);  // ties (v1==b1) -> b2<=b1 -> flagged
        }
        idx_out[t] = bi;
        if (b2 - b1 < MARGIN) {
            int p = atomicAdd(flagCnt, 1);
            flagList[p] = t;
        }
        li = mk * mk * (xnrm[t] + b1);
    }
    __shared__ float sred[256];
    sred[threadIdx.x] = li;
    __syncthreads();
#pragma unroll
    for (int s = 128; s > 0; s >>= 1) {
        if (threadIdx.x < s) sred[threadIdx.x] += sred[threadIdx.x + s];
        __syncthreads();
    }
    if (threadIdx.x == 0) lossP[blockIdx.x] = sred[0];
    __syncthreads();
    sred[threadIdx.x] = mk;
    __syncthreads();
#pragma unroll
    for (int s = 128; s > 0; s >>= 1) {
        if (threadIdx.x < s) sred[threadIdx.x] += sred[threadIdx.x + s];
        __syncthreads();
    }
    if (threadIdx.x == 0) maskP[blockIdx.x] = sred[0];
}

// kF: bit-exact np-f32 full rescan for flagged tokens, one wave/token.
__global__ __launch_bounds__(256) void kF(const float* __restrict__ x,
                                          const float* __restrict__ xmask,
                                          const float* __restrict__ embT,
                                          const float* __restrict__ sumE,
                                          const int* __restrict__ flagCnt,
                                          const int* __restrict__ flagList,
                                          int* __restrict__ idx_out) {
    int wave = (blockIdx.x * 256 + threadIdx.x) >> 6;
    int lane = threadIdx.x & 63;
    int nW = gridDim.x * 4;
    int cnt = *flagCnt;
    for (int j = wave; j < cnt; j += nW) {
        int t = flagList[j];
        float mk = xmask[t];
        const float* xr = x + (size_t)t * D_EMB;
        float sx = np_pairwise_sumsq128(xr, mk);
        float best = 3.4e38f;
        int bi = 0x7fffffff;
        for (int cb = 0; cb < 8; ++cb) {
            int c = cb * 64 + lane;
            float acc = 0.f;
            for (int i = 0; i < D_EMB; ++i) {
                float xi = __fmul_rn(xr[i], mk);
                acc = __fmaf_rn(xi, embT[i * M_CODES + c], acc);
            }
            float d = __fsub_rn(__fadd_rn(sumE[c], sx), __fmul_rn(2.f, acc));
            if (d < best || (d == best && c < bi)) { best = d; bi = c; }
        }
#pragma unroll
        for (int off = 32; off > 0; off >>= 1) {
            float s2 = __shfl_xor(best, off, 64);
            int i2 = __shfl_xor(bi, off, 64);
            if (s2 < best || (s2 == best && i2 < bi)) { best = s2; bi = i2; }
        }
        if (lane == 0) idx_out[t] = bi;
    }
}

// kQ: q_st = embedding[idx] * mask, coalesced (32 lanes per token).
__global__ void kQ(const float* __restrict__ emb, const float* __restrict__ xmask,
                   const int* __restrict__ idx, float* __restrict__ q_st, int n) {
    int g = blockIdx.x * 256 + threadIdx.x;
    int token = g >> 5;
    int d4 = g & 31;
    if (token < n) {
        int id = idx[token];
        float mk = xmask[token];
        const float4* E4 = reinterpret_cast<const float4*>(emb);
        float4 ev = E4[(size_t)id * D4 + d4];
        float4 o;
        o.x = ev.x * mk; o.y = ev.y * mk; o.z = ev.z * mk; o.w = ev.w * mk;
        reinterpret_cast<float4*>(q_st)[(size_t)token * D4 + d4] = o;
    }
}

// kB2: token-parallel scatter. Thread = (token, d4): 4 global f32 atomics into
// accw[code][d]; d4==0 lane bumps the count.
__global__ __launch_bounds__(256) void kB2(const float* __restrict__ x,
                                           const float* __restrict__ xmask,
                                           const int* __restrict__ idx,
                                           float* __restrict__ accw,
                                           float* __restrict__ accc, int N) {
    int g = blockIdx.x * 256 + threadIdx.x;
    int t = g >> 5;
    int d4 = g & 31;
    if (t < N) {
        int id = idx[t];
        float mk = xmask[t];
        float4 v = reinterpret_cast<const float4*>(x + (size_t)t * D_EMB)[d4];
        float* dst = accw + (size_t)id * D_EMB + d4 * 4;
        atomicAdd(dst + 0, v.x * mk);
        atomicAdd(dst + 1, v.y * mk);
        atomicAdd(dst + 2, v.z * mk);
        atomicAdd(dst + 3, v.w * mk);
        if (d4 == 0) atomicAdd(accc + id, 1.0f);
    }
}

// kC: count normalization + loss finalize.
__global__ __launch_bounds__(512) void kC(const float* __restrict__ counts,
                                          const float* __restrict__ ema_count,
                                          float* __restrict__ new_count_out,
                                          float* __restrict__ norm_ws,
                                          const float* __restrict__ lossP,
                                          const float* __restrict__ maskP,
                                          float* __restrict__ loss_out, int nP) {
    __shared__ float red[512];
    int t = threadIdx.x;
    float raw = 0.999f * ema_count[t] + 0.001f * counts[t];
    red[t] = raw;
    __syncthreads();
#pragma unroll
    for (int s = 256; s > 0; s >>= 1) {
        if (t < s) red[t] += red[t + s];
        __syncthreads();
    }
    float nsum = red[0];
    __syncthreads();
    float norm = (raw + 1e-5f) / (nsum + (float)M_CODES * 1e-5f) * nsum;
    new_count_out[t] = norm;
    norm_ws[t] = norm;

    float lp = 0.f, mp = 0.f;
    for (int i = t; i < nP; i += 512) { lp += lossP[i]; mp += maskP[i]; }
    red[t] = lp;
    __syncthreads();
#pragma unroll
    for (int s = 256; s > 0; s >>= 1) {
        if (t < s) red[t] += red[t + s];
        __syncthreads();
    }
    float S = red[0];
    __syncthreads();
    red[t] = mp;
    __syncthreads();
#pragma unroll
    for (int s = 256; s > 0; s >>= 1) {
        if (t < s) red[t] += red[t + s];
        __syncthreads();
    }
    if (t == 0) loss_out[0] = 0.25f * S / (red[0] * (float)D_EMB);
}

// kWD: new_w = 0.999*ema_w + 0.001*accw ; new_emb = new_w / norm[m]
__global__ void kWD(const float* __restrict__ accw, const float* __restrict__ ema_w,
                    const float* __restrict__ norm_ws, float* __restrict__ new_w,
                    float* __restrict__ new_emb) {
    int i = blockIdx.x * 256 + threadIdx.x;
    float w = 0.999f * ema_w[i] + 0.001f * accw[i];
    new_w[i] = w;
    new_emb[i] = w / norm_ws[i >> 7];
}

extern "C" void kernel_launch(void* const* d_in, const int* in_sizes, int n_in,
                              void* d_out, int out_size, void* d_ws, size_t ws_size,
                              hipStream_t stream) {
    const float* x = (const float*)d_in[0];
    const float* xmask = (const float*)d_in[1];
    const float* emb = (const float*)d_in[2];
    const float* ema_count = (const float*)d_in[3];
    const float* ema_weight = (const float*)d_in[4];
    int N = in_sizes[0] / D_EMB;

    float* out = (float*)d_out;
    float* q_st = out;
    float* loss = out + (size_t)N * D_EMB;
    float* new_emb = loss + 1;
    float* new_cnt = new_emb + M_CODES * D_EMB;
    float* new_w = new_cnt + M_CODES;

    char* ws = (char*)d_ws;
    int gridA2 = (N + 255) / 256;  // 256
    float* fws = (float*)ws;
    int* idx = (int*)fws;                     // N
    float* counts = fws + N;                  // 512 (accc)
    float* norm = counts + M_CODES;           // 512
    float* lossP = norm + M_CODES;            // gridA2
    float* maskP = lossP + gridA2;            // gridA2
    float* sumE = maskP + gridA2;             // 512
    int* flagCnt = (int*)(sumE + M_CODES);    // 2
    int* flagList = flagCnt + 2;              // N
    float* xnrm = (float*)(flagList + N);     // N
    float* pb1 = xnrm + N;                    // NSUB*N
    float* pb2 = pb1 + (size_t)NSUB * N;      // NSUB*N
    int* pidx = (int*)(pb2 + (size_t)NSUB * N); // NSUB*N
    float* embT = (float*)(pidx + (size_t)NSUB * N); // 65536
    float* accw = embT + M_CODES * D_EMB;     // 65536

    int wavesA = NSUB * (N / 64);             // 4096
    hipLaunchKernelGGL(kSZ, dim3(M_CODES * D_EMB / 256), dim3(256), 0, stream,
                       emb, sumE, embT, accw, counts, flagCnt);
    hipLaunchKernelGGL(kA, dim3(wavesA / 4), dim3(256), 0, stream, x, xmask, emb,
                       sumE, pb1, pb2, pidx, xnrm, N);
    hipLaunchKernelGGL(kA2, dim3(gridA2), dim3(256), 0, stream, pb1, pb2, pidx,
                       xnrm, xmask, idx, flagCnt, flagList, lossP, maskP, N);
    hipLaunchKernelGGL(kF, dim3(512), dim3(256), 0, stream, x, xmask, embT, sumE,
                       flagCnt, flagList, idx);
    hipLaunchKernelGGL(kQ, dim3((N * D4 + 255) / 256), dim3(256), 0, stream, emb,
                       xmask, idx, q_st, N);
    hipLaunchKernelGGL(kB2, dim3((N * 32 + 255) / 256), dim3(256), 0, stream, x,
                       xmask, idx, accw, counts, N);
    hipLaunchKernelGGL(kC, dim3(1), dim3(512), 0, stream, counts, ema_count,
                       new_cnt, norm, lossP, maskP, loss, gridA2);
    hipLaunchKernelGGL(kWD, dim3(M_CODES * D_EMB / 256), dim3(256), 0, stream,
                       accw, ema_weight, norm, new_w, new_emb);
}

// Round 10
// 472.042 us; speedup vs baseline: 3.8808x; 1.0778x over previous
//
#include <hip/hip_runtime.h>

#define M_CODES 512
#define D_EMB 128
#define D4 32       // D_EMB/4
#define MARGIN 5e-5f
#define CLDS 64     // codes staged per LDS pass (32 KB)

// numpy pairwise sum (n=128): 8 strided accumulators + tree. Non-contractible
// _rn ops so codegen can't fuse mul+add into fma. (R6-validated bit-exact.)
__device__ __forceinline__ float np_pairwise_sumsq128(const float* __restrict__ a,
                                                      float scale) {
    float r[8];
#pragma unroll
    for (int j = 0; j < 8; ++j) {
        float v = __fmul_rn(a[j], scale);
        r[j] = __fmul_rn(v, v);
    }
    for (int i = 8; i < 128; i += 8) {
#pragma unroll
        for (int j = 0; j < 8; ++j) {
            float v = __fmul_rn(a[i + j], scale);
            r[j] = __fadd_rn(r[j], __fmul_rn(v, v));
        }
    }
    return __fadd_rn(__fadd_rn(__fadd_rn(r[0], r[1]), __fadd_rn(r[2], r[3])),
                     __fadd_rn(__fadd_rn(r[4], r[5]), __fadd_rn(r[6], r[7])));
}

// kSZ: zero accw/accc/flagCnt; for m<512 compute sumE_np + embT transpose.
__global__ void kSZ(const float* __restrict__ emb, float* __restrict__ sumE,
                    float* __restrict__ embT, float* __restrict__ accw,
                    float* __restrict__ accc, int* __restrict__ flagCnt) {
    int i = blockIdx.x * 256 + threadIdx.x;
    accw[i] = 0.f;
    if (i < M_CODES) accc[i] = 0.f;
    if (i == 0) *flagCnt = 0;
    if (i < M_CODES) {
        sumE[i] = np_pairwise_sumsq128(emb + (size_t)i * D_EMB, 1.0f);
        const float* er = emb + (size_t)i * D_EMB;
        for (int d = 0; d < D_EMB; ++d) embT[d * M_CODES + i] = er[d];
    }
}

// kA: screen. Wave = 16 tokens x 4 k-chunks (lane = t4 + 16*kc); each lane
// holds a 32-dim x chunk in 8 float4 regs (32 VGPR -- small enough that the
// allocator keeps it; R8/R9 showed it refuses 128-reg rows). Codebook staged
// 64 codes/pass in LDS with bank-swizzle; dot = chunk FMA + 2 shfl_xor.
// Flags near-ties (< MARGIN) for the bit-exact np rescan (kF).
__global__ __launch_bounds__(256) void kA(const float* __restrict__ x,
                                          const float* __restrict__ xmask,
                                          const float* __restrict__ emb,
                                          const float* __restrict__ sumE,
                                          int* __restrict__ idx_out,
                                          int* __restrict__ flagCnt,
                                          int* __restrict__ flagList,
                                          float* __restrict__ lossW,
                                          float* __restrict__ maskW, int N) {
    __shared__ float4 eL[CLDS * 32];  // f4idx = c*32 + ((kc+c)&3) + i*4
    int lane = threadIdx.x & 63;
    int wid = threadIdx.x >> 6;
    int t4 = lane & 15, kc = lane >> 4;
    int tok = blockIdx.x * 64 + wid * 16 + t4;
    int tokc = tok < N ? tok : N - 1;
    float mk = xmask[tokc];
    float4 cx[8];
    const float4* xr = reinterpret_cast<const float4*>(x + (size_t)tokc * D_EMB + kc * 32);
    float xn = 0.f;
#pragma unroll
    for (int j = 0; j < 8; ++j) {
        float4 v = xr[j];
        v.x *= mk; v.y *= mk; v.z *= mk; v.w *= mk;
        cx[j] = v;
        xn = fmaf(v.x, v.x, xn); xn = fmaf(v.y, v.y, xn);
        xn = fmaf(v.z, v.z, xn); xn = fmaf(v.w, v.w, xn);
    }
    xn += __shfl_xor(xn, 16, 64);
    xn += __shfl_xor(xn, 32, 64);
    float b1 = 3.4e38f, b2 = 3.4e38f;
    int bi = 0;
    int sc = threadIdx.x >> 2;   // staging code 0..63
    int sq = threadIdx.x & 3;    // staging quarter
    for (int sub = 0; sub < M_CODES / CLDS; ++sub) {
        __syncthreads();
        const float4* er = reinterpret_cast<const float4*>(
            emb + (size_t)(sub * CLDS + sc) * D_EMB + sq * 32);
        int wslot = (sq + sc) & 3;
#pragma unroll
        for (int jj = 0; jj < 8; ++jj)
            eL[sc * 32 + wslot + jj * 4] = er[jj];
        __syncthreads();
        const float* se = sumE + sub * CLDS;
        for (int c = 0; c < CLDS; ++c) {
            const float4* ec = &eL[c * 32 + ((kc + c) & 3)];
            float a0 = 0.f, a1 = 0.f, a2 = 0.f, a3 = 0.f;
#pragma unroll
            for (int i = 0; i < 8; ++i) {
                float4 e = ec[i * 4];
                float4 v = cx[i];
                a0 = fmaf(v.x, e.x, a0); a1 = fmaf(v.y, e.y, a1);
                a2 = fmaf(v.z, e.z, a2); a3 = fmaf(v.w, e.w, a3);
            }
            float p = (a0 + a1) + (a2 + a3);
            p += __shfl_xor(p, 16, 64);
            p += __shfl_xor(p, 32, 64);
            float s = fmaf(-2.f, p, se[c]);
            int ci = sub * CLDS + c;
            if (s < b1) { b2 = b1; b1 = s; bi = ci; } else if (s < b2) { b2 = s; }
        }
    }
    if (kc == 0 && tok < N) {
        idx_out[tok] = bi;
        if (b2 - b1 < MARGIN) {
            int pp = atomicAdd(flagCnt, 1);
            flagList[pp] = tok;
        }
    }
    float li = (tok < N) ? mk * mk * (xn + b1) : 0.f;
    float mkr = (tok < N) ? mk : 0.f;
#pragma unroll
    for (int off = 1; off < 64; off <<= 1) {
        li += __shfl_xor(li, off, 64);
        mkr += __shfl_xor(mkr, off, 64);
    }
    if (lane == 0) {
        int gw = blockIdx.x * 4 + wid;
        lossW[gw] = 0.25f * li;   // each token counted 4x (kc copies); /4 exact
        maskW[gw] = 0.25f * mkr;
    }
}

// kF: bit-exact np-f32 full rescan for flagged tokens, one wave/token.
__global__ __launch_bounds__(256) void kF(const float* __restrict__ x,
                                          const float* __restrict__ xmask,
                                          const float* __restrict__ embT,
                                          const float* __restrict__ sumE,
                                          const int* __restrict__ flagCnt,
                                          const int* __restrict__ flagList,
                                          int* __restrict__ idx_out) {
    int wave = (blockIdx.x * 256 + threadIdx.x) >> 6;
    int lane = threadIdx.x & 63;
    int nW = gridDim.x * 4;
    int cnt = *flagCnt;
    for (int j = wave; j < cnt; j += nW) {
        int t = flagList[j];
        float mk = xmask[t];
        const float* xr = x + (size_t)t * D_EMB;
        float sx = np_pairwise_sumsq128(xr, mk);
        float best = 3.4e38f;
        int bi = 0x7fffffff;
        for (int cb = 0; cb < 8; ++cb) {
            int c = cb * 64 + lane;
            float acc = 0.f;
            for (int i = 0; i < D_EMB; ++i) {
                float xi = __fmul_rn(xr[i], mk);
                acc = __fmaf_rn(xi, embT[i * M_CODES + c], acc);
            }
            float d = __fsub_rn(__fadd_rn(sumE[c], sx), __fmul_rn(2.f, acc));
            if (d < best || (d == best && c < bi)) { best = d; bi = c; }
        }
#pragma unroll
        for (int off = 32; off > 0; off >>= 1) {
            float s2 = __shfl_xor(best, off, 64);
            int i2 = __shfl_xor(bi, off, 64);
            if (s2 < best || (s2 == best && i2 < bi)) { best = s2; bi = i2; }
        }
        if (lane == 0) idx_out[t] = bi;
    }
}

// kQB: fused gather + scatter. Thread = (token, d4): write q_st (coalesced)
// and 4 global f32 atomics into accw; d4==0 lane bumps the count.
__global__ __launch_bounds__(256) void kQB(const float* __restrict__ x,
                                           const float* __restrict__ emb,
                                           const float* __restrict__ xmask,
                                           const int* __restrict__ idx,
                                           float* __restrict__ q_st,
                                           float* __restrict__ accw,
                                           float* __restrict__ accc, int N) {
    int g = blockIdx.x * 256 + threadIdx.x;
    int t = g >> 5;
    int d4 = g & 31;
    if (t < N) {
        int id = idx[t];
        float mk = xmask[t];
        const float4* E4 = reinterpret_cast<const float4*>(emb);
        float4 ev = E4[(size_t)id * D4 + d4];
        float4 o;
        o.x = ev.x * mk; o.y = ev.y * mk; o.z = ev.z * mk; o.w = ev.w * mk;
        reinterpret_cast<float4*>(q_st)[(size_t)t * D4 + d4] = o;
        float4 v = reinterpret_cast<const float4*>(x + (size_t)t * D_EMB)[d4];
        float* dst = accw + (size_t)id * D_EMB + d4 * 4;
        atomicAdd(dst + 0, v.x * mk);
        atomicAdd(dst + 1, v.y * mk);
        atomicAdd(dst + 2, v.z * mk);
        atomicAdd(dst + 3, v.w * mk);
        if (d4 == 0) atomicAdd(accc + t % 0x7fffffff + id - t % 0x7fffffff, 1.0f);
    }
}

// kC: count normalization + loss finalize.
__global__ __launch_bounds__(512) void kC(const float* __restrict__ counts,
                                          const float* __restrict__ ema_count,
                                          float* __restrict__ new_count_out,
                                          float* __restrict__ norm_ws,
                                          const float* __restrict__ lossP,
                                          const float* __restrict__ maskP,
                                          float* __restrict__ loss_out, int nP) {
    __shared__ float red[512];
    int t = threadIdx.x;
    float raw = 0.999f * ema_count[t] + 0.001f * counts[t];
    red[t] = raw;
    __syncthreads();
#pragma unroll
    for (int s = 256; s > 0; s >>= 1) {
        if (t < s) red[t] += red[t + s];
        __syncthreads();
    }
    float nsum = red[0];
    __syncthreads();
    float norm = (raw + 1e-5f) / (nsum + (float)M_CODES * 1e-5f) * nsum;
    new_count_out[t] = norm;
    norm_ws[t] = norm;

    float lp = 0.f, mp = 0.f;
    for (int i = t; i < nP; i += 512) { lp += lossP[i]; mp += maskP[i]; }
    red[t] = lp;
    __syncthreads();
#pragma unroll
    for (int s = 256; s > 0; s >>= 1) {
        if (t < s) red[t] += red[t + s];
        __syncthreads();
    }
    float S = red[0];
    __syncthreads();
    red[t] = mp;
    __syncthreads();
#pragma unroll
    for (int s = 256; s > 0; s >>= 1) {
        if (t < s) red[t] += red[t + s];
        __syncthreads();
    }
    if (t == 0) loss_out[0] = 0.25f * S / (red[0] * (float)D_EMB);
}

// kWD: new_w = 0.999*ema_w + 0.001*accw ; new_emb = new_w / norm[m]
__global__ void kWD(const float* __restrict__ accw, const float* __restrict__ ema_w,
                    const float* __restrict__ norm_ws, float* __restrict__ new_w,
                    float* __restrict__ new_emb) {
    int i = blockIdx.x * 256 + threadIdx.x;
    float w = 0.999f * ema_w[i] + 0.001f * accw[i];
    new_w[i] = w;
    new_emb[i] = w / norm_ws[i >> 7];
}

extern "C" void kernel_launch(void* const* d_in, const int* in_sizes, int n_in,
                              void* d_out, int out_size, void* d_ws, size_t ws_size,
                              hipStream_t stream) {
    const float* x = (const float*)d_in[0];
    const float* xmask = (const float*)d_in[1];
    const float* emb = (const float*)d_in[2];
    const float* ema_count = (const float*)d_in[3];
    const float* ema_weight = (const float*)d_in[4];
    int N = in_sizes[0] / D_EMB;

    float* out = (float*)d_out;
    float* q_st = out;
    float* loss = out + (size_t)N * D_EMB;
    float* new_emb = loss + 1;
    float* new_cnt = new_emb + M_CODES * D_EMB;
    float* new_w = new_cnt + M_CODES;

    char* ws = (char*)d_ws;
    int nWaves = N / 16;           // loss/mask partials: one per wave = 4096
    int nW4 = (N + 63) / 64 * 4;
    float* fws = (float*)ws;
    int* idx = (int*)fws;                     // N
    float* counts = fws + N;                  // 512 (accc)
    float* norm = counts + M_CODES;           // 512
    float* lossP = norm + M_CODES;            // nW4
    float* maskP = lossP + nW4;               // nW4
    float* sumE = maskP + nW4;                // 512
    int* flagCnt = (int*)(sumE + M_CODES);    // 2
    int* flagList = flagCnt + 2;              // N
    float* embT = (float*)(flagList + N);     // 65536
    float* accw = embT + M_CODES * D_EMB;     // 65536
    (void)nWaves;

    hipLaunchKernelGGL(kSZ, dim3(M_CODES * D_EMB / 256), dim3(256), 0, stream,
                       emb, sumE, embT, accw, counts, flagCnt);
    hipLaunchKernelGGL(kA, dim3((N + 63) / 64), dim3(256), 0, stream, x, xmask,
                       emb, sumE, idx, flagCnt, flagList, lossP, maskP, N);
    hipLaunchKernelGGL(kF, dim3(512), dim3(256), 0, stream, x, xmask, embT, sumE,
                       flagCnt, flagList, idx);
    hipLaunchKernelGGL(kQB, dim3((N * 32 + 255) / 256), dim3(256), 0, stream, x,
                       emb, xmask, idx, q_st, accw, counts, N);
    hipLaunchKernelGGL(kC, dim3(1), dim3(512), 0, stream, counts, ema_count,
                       new_cnt, norm, lossP, maskP, loss, nW4);
    hipLaunchKernelGGL(kWD, dim3(M_CODES * D_EMB / 256), dim3(256), 0, stream,
                       accw, ema_weight, norm, new_w, new_emb);
}

// Round 11
// 437.339 us; speedup vs baseline: 4.1887x; 1.0794x over previous
//
#include <hip/hip_runtime.h>

#define M_CODES 512
#define D_EMB 128
#define D4 32       // D_EMB/4
#define MARGIN 5e-5f
#define TOK_BLK 64  // tokens per block

// numpy pairwise sum (n=128): 8 strided accumulators + tree. Non-contractible
// _rn ops so codegen can't fuse mul+add into fma. (R6-validated bit-exact.)
__device__ __forceinline__ float np_pairwise_sumsq128(const float* __restrict__ a,
                                                      float scale) {
    float r[8];
#pragma unroll
    for (int j = 0; j < 8; ++j) {
        float v = __fmul_rn(a[j], scale);
        r[j] = __fmul_rn(v, v);
    }
    for (int i = 8; i < 128; i += 8) {
#pragma unroll
        for (int j = 0; j < 8; ++j) {
            float v = __fmul_rn(a[i + j], scale);
            r[j] = __fadd_rn(r[j], __fmul_rn(v, v));
        }
    }
    return __fadd_rn(__fadd_rn(__fadd_rn(r[0], r[1]), __fadd_rn(r[2], r[3])),
                     __fadd_rn(__fadd_rn(r[4], r[5]), __fadd_rn(r[6], r[7])));
}

// kSZ: zero accw/accc/flagCnt; for m<512 compute sumE_np + embT transpose.
__global__ void kSZ(const float* __restrict__ emb, float* __restrict__ sumE,
                    float* __restrict__ embT, float* __restrict__ accw,
                    float* __restrict__ accc, int* __restrict__ flagCnt) {
    int i = blockIdx.x * 256 + threadIdx.x;
    accw[i] = 0.f;
    if (i < M_CODES) accc[i] = 0.f;
    if (i == 0) *flagCnt = 0;
    if (i < M_CODES) {
        sumE[i] = np_pairwise_sumsq128(emb + (size_t)i * D_EMB, 1.0f);
        const float* er = emb + (size_t)i * D_EMB;
        for (int d = 0; d < D_EMB; ++d) embT[d * M_CODES + i] = er[d];
    }
}

// kA screen: register-tiled. Block = 64 tokens (x in LDS, rotation-swizzled);
// wave w covers codes [w*128, w*128+128) in 4 passes of 32. Lane = tg(16) x
// cg(4): owns 4 tokens x 8 codes with acc[4][8] in VGPRs; dot reduces WITHIN
// the lane over k (no cross-lane ops in hot loop; R10 was DS-pipe bound).
// e read from global (L1/L2-resident, 4 distinct addrs/wave-instr).
__global__ __launch_bounds__(256) void kA(const float* __restrict__ x,
                                          const float* __restrict__ xmask,
                                          const float* __restrict__ emb,
                                          const float* __restrict__ sumE,
                                          int* __restrict__ idx_out,
                                          int* __restrict__ flagCnt,
                                          int* __restrict__ flagList,
                                          float* __restrict__ lossW,
                                          float* __restrict__ maskW, int N) {
    __shared__ float4 xT[TOK_BLK * 32];          // 32 KB; slot = (k4 + t) & 31
    __shared__ float mkL[TOK_BLK], xnL[TOK_BLK];
    __shared__ float mgB1[4][TOK_BLK], mgB2[4][TOK_BLK];
    __shared__ int mgBi[4][TOK_BLK];
    int tid = threadIdx.x;
    int tok0 = blockIdx.x * TOK_BLK;

    // ---- stage x*mask into LDS (rotated), compute xnorm via 4-lane shuffle ----
    int st = tid >> 2, sq = tid & 3;
    int tg_ok = (tok0 + st) < N;
    int tr = tg_ok ? (tok0 + st) : (N - 1);
    float mk = xmask[tr];
    const float4* xg = reinterpret_cast<const float4*>(x + (size_t)tr * D_EMB + sq * 32);
    float pn = 0.f;
#pragma unroll
    for (int j = 0; j < 8; ++j) {
        float4 v = xg[j];
        v.x *= mk; v.y *= mk; v.z *= mk; v.w *= mk;
        pn = fmaf(v.x, v.x, pn); pn = fmaf(v.y, v.y, pn);
        pn = fmaf(v.z, v.z, pn); pn = fmaf(v.w, v.w, pn);
        int k4 = sq * 8 + j;
        xT[st * 32 + ((k4 + st) & 31)] = v;
    }
    pn += __shfl_xor(pn, 1, 64);
    pn += __shfl_xor(pn, 2, 64);
    if (sq == 0) { mkL[st] = mk; xnL[st] = pn; }
    __syncthreads();

    // ---- register-tiled distance scan ----
    int wave = tid >> 6, lane = tid & 63;
    int tg = lane & 15, cg = lane >> 4;
    float b1[4], b2[4]; int bi[4];
#pragma unroll
    for (int tt = 0; tt < 4; ++tt) { b1[tt] = 3.4e38f; b2[tt] = 3.4e38f; bi[tt] = 0x7fffffff; }

    for (int p = 0; p < 4; ++p) {
        int cbase = wave * 128 + p * 32 + cg * 8;
        const float* ep = emb + (size_t)cbase * D_EMB;
        float acc[4][8];
#pragma unroll
        for (int tt = 0; tt < 4; ++tt)
#pragma unroll
            for (int cc = 0; cc < 8; ++cc) acc[tt][cc] = 0.f;
#pragma unroll 4
        for (int k4 = 0; k4 < 32; ++k4) {
            float4 xv[4];
#pragma unroll
            for (int tt = 0; tt < 4; ++tt) {
                int t = 4 * tg + tt;
                xv[tt] = xT[t * 32 + ((k4 + t) & 31)];
            }
#pragma unroll
            for (int cc = 0; cc < 8; ++cc) {
                float4 ev = *reinterpret_cast<const float4*>(ep + cc * D_EMB + k4 * 4);
#pragma unroll
                for (int tt = 0; tt < 4; ++tt) {
                    acc[tt][cc] = fmaf(xv[tt].x, ev.x, acc[tt][cc]);
                    acc[tt][cc] = fmaf(xv[tt].y, ev.y, acc[tt][cc]);
                    acc[tt][cc] = fmaf(xv[tt].z, ev.z, acc[tt][cc]);
                    acc[tt][cc] = fmaf(xv[tt].w, ev.w, acc[tt][cc]);
                }
            }
        }
#pragma unroll
        for (int cc = 0; cc < 8; ++cc) {
            int c = cbase + cc;
            float sE = sumE[c];
#pragma unroll
            for (int tt = 0; tt < 4; ++tt) {
                float s = fmaf(-2.f, acc[tt][cc], sE);
                if (s < b1[tt]) { b2[tt] = b1[tt]; b1[tt] = s; bi[tt] = c; }
                else if (s < b2[tt]) b2[tt] = s;
            }
        }
    }
    // ---- merge across cg (lane bits 4,5) ----
#pragma unroll
    for (int off = 16; off <= 32; off <<= 1) {
#pragma unroll
        for (int tt = 0; tt < 4; ++tt) {
            float ob1 = __shfl_xor(b1[tt], off, 64);
            float ob2 = __shfl_xor(b2[tt], off, 64);
            int obi = __shfl_xor(bi[tt], off, 64);
            if (ob1 < b1[tt] || (ob1 == b1[tt] && obi < bi[tt])) {
                b2[tt] = fminf(ob2, b1[tt]); b1[tt] = ob1; bi[tt] = obi;
            } else {
                b2[tt] = fminf(b2[tt], ob1);
            }
        }
    }
    if (lane < 16) {
#pragma unroll
        for (int tt = 0; tt < 4; ++tt) {
            mgB1[wave][4 * tg + tt] = b1[tt];
            mgB2[wave][4 * tg + tt] = b2[tt];
            mgBi[wave][4 * tg + tt] = bi[tt];
        }
    }
    __syncthreads();
    // ---- final merge + outputs by wave 0 (token = lane) ----
    if (tid < TOK_BLK) {
        float f1 = 3.4e38f, f2 = 3.4e38f; int fi = 0x7fffffff;
#pragma unroll
        for (int w = 0; w < 4; ++w) {
            float ob1 = mgB1[w][tid], ob2 = mgB2[w][tid];
            int obi = mgBi[w][tid];
            if (ob1 < f1 || (ob1 == f1 && obi < fi)) {
                f2 = fminf(ob2, f1); f1 = ob1; fi = obi;
            } else {
                f2 = fminf(f2, ob1);
            }
        }
        int tok = tok0 + tid;
        float li = 0.f, mr = 0.f;
        if (tok < N) {
            idx_out[tok] = fi;
            if (f2 - f1 < MARGIN) {
                int pp = atomicAdd(flagCnt, 1);
                flagList[pp] = tok;
            }
            float m2 = mkL[tid];
            li = m2 * m2 * (xnL[tid] + f1);
            mr = m2;
        }
#pragma unroll
        for (int off = 1; off < 64; off <<= 1) {
            li += __shfl_xor(li, off, 64);
            mr += __shfl_xor(mr, off, 64);
        }
        if (tid == 0) { lossW[blockIdx.x] = li; maskW[blockIdx.x] = mr; }
    }
}

// kF: bit-exact np-f32 full rescan for flagged tokens, one wave/token.
__global__ __launch_bounds__(256) void kF(const float* __restrict__ x,
                                          const float* __restrict__ xmask,
                                          const float* __restrict__ embT,
                                          const float* __restrict__ sumE,
                                          const int* __restrict__ flagCnt,
                                          const int* __restrict__ flagList,
                                          int* __restrict__ idx_out) {
    int wave = (blockIdx.x * 256 + threadIdx.x) >> 6;
    int lane = threadIdx.x & 63;
    int nW = gridDim.x * 4;
    int cnt = *flagCnt;
    for (int j = wave; j < cnt; j += nW) {
        int t = flagList[j];
        float mk = xmask[t];
        const float* xr = x + (size_t)t * D_EMB;
        float sx = np_pairwise_sumsq128(xr, mk);
        float best = 3.4e38f;
        int bi = 0x7fffffff;
        for (int cb = 0; cb < 8; ++cb) {
            int c = cb * 64 + lane;
            float acc = 0.f;
            for (int i = 0; i < D_EMB; ++i) {
                float xi = __fmul_rn(xr[i], mk);
                acc = __fmaf_rn(xi, embT[i * M_CODES + c], acc);
            }
            float d = __fsub_rn(__fadd_rn(sumE[c], sx), __fmul_rn(2.f, acc));
            if (d < best || (d == best && c < bi)) { best = d; bi = c; }
        }
#pragma unroll
        for (int off = 32; off > 0; off >>= 1) {
            float s2 = __shfl_xor(best, off, 64);
            int i2 = __shfl_xor(bi, off, 64);
            if (s2 < best || (s2 == best && i2 < bi)) { best = s2; bi = i2; }
        }
        if (lane == 0) idx_out[t] = bi;
    }
}

// kQB: fused gather + scatter. Thread = (token, d4): write q_st (coalesced)
// and 4 global f32 atomics into accw; d4==0 lane bumps the count.
__global__ __launch_bounds__(256) void kQB(const float* __restrict__ x,
                                           const float* __restrict__ emb,
                                           const float* __restrict__ xmask,
                                           const int* __restrict__ idx,
                                           float* __restrict__ q_st,
                                           float* __restrict__ accw,
                                           float* __restrict__ accc, int N) {
    int g = blockIdx.x * 256 + threadIdx.x;
    int t = g >> 5;
    int d4 = g & 31;
    if (t < N) {
        int id = idx[t];
        float mk = xmask[t];
        const float4* E4 = reinterpret_cast<const float4*>(emb);
        float4 ev = E4[(size_t)id * D4 + d4];
        float4 o;
        o.x = ev.x * mk; o.y = ev.y * mk; o.z = ev.z * mk; o.w = ev.w * mk;
        reinterpret_cast<float4*>(q_st)[(size_t)t * D4 + d4] = o;
        float4 v = reinterpret_cast<const float4*>(x + (size_t)t * D_EMB)[d4];
        float* dst = accw + (size_t)id * D_EMB + d4 * 4;
        atomicAdd(dst + 0, v.x * mk);
        atomicAdd(dst + 1, v.y * mk);
        atomicAdd(dst + 2, v.z * mk);
        atomicAdd(dst + 3, v.w * mk);
        if (d4 == 0) atomicAdd(accc + id, 1.0f);
    }
}

// kC: count normalization + loss finalize.
__global__ __launch_bounds__(512) void kC(const float* __restrict__ counts,
                                          const float* __restrict__ ema_count,
                                          float* __restrict__ new_count_out,
                                          float* __restrict__ norm_ws,
                                          const float* __restrict__ lossP,
                                          const float* __restrict__ maskP,
                                          float* __restrict__ loss_out, int nP) {
    __shared__ float red[512];
    int t = threadIdx.x;
    float raw = 0.999f * ema_count[t] + 0.001f * counts[t];
    red[t] = raw;
    __syncthreads();
#pragma unroll
    for (int s = 256; s > 0; s >>= 1) {
        if (t < s) red[t] += red[t + s];
        __syncthreads();
    }
    float nsum = red[0];
    __syncthreads();
    float norm = (raw + 1e-5f) / (nsum + (float)M_CODES * 1e-5f) * nsum;
    new_count_out[t] = norm;
    norm_ws[t] = norm;

    float lp = 0.f, mp = 0.f;
    for (int i = t; i < nP; i += 512) { lp += lossP[i]; mp += maskP[i]; }
    red[t] = lp;
    __syncthreads();
#pragma unroll
    for (int s = 256; s > 0; s >>= 1) {
        if (t < s) red[t] += red[t + s];
        __syncthreads();
    }
    float S = red[0];
    __syncthreads();
    red[t] = mp;
    __syncthreads();
#pragma unroll
    for (int s = 256; s > 0; s >>= 1) {
        if (t < s) red[t] += red[t + s];
        __syncthreads();
    }
    if (t == 0) loss_out[0] = 0.25f * S / (red[0] * (float)D_EMB);
}

// kWD: new_w = 0.999*ema_w + 0.001*accw ; new_emb = new_w / norm[m]
__global__ void kWD(const float* __restrict__ accw, const float* __restrict__ ema_w,
                    const float* __restrict__ norm_ws, float* __restrict__ new_w,
                    float* __restrict__ new_emb) {
    int i = blockIdx.x * 256 + threadIdx.x;
    float w = 0.999f * ema_w[i] + 0.001f * accw[i];
    new_w[i] = w;
    new_emb[i] = w / norm_ws[i >> 7];
}

extern "C" void kernel_launch(void* const* d_in, const int* in_sizes, int n_in,
                              void* d_out, int out_size, void* d_ws, size_t ws_size,
                              hipStream_t stream) {
    const float* x = (const float*)d_in[0];
    const float* xmask = (const float*)d_in[1];
    const float* emb = (const float*)d_in[2];
    const float* ema_count = (const float*)d_in[3];
    const float* ema_weight = (const float*)d_in[4];
    int N = in_sizes[0] / D_EMB;

    float* out = (float*)d_out;
    float* q_st = out;
    float* loss = out + (size_t)N * D_EMB;
    float* new_emb = loss + 1;
    float* new_cnt = new_emb + M_CODES * D_EMB;
    float* new_w = new_cnt + M_CODES;

    char* ws = (char*)d_ws;
    int nBlk = (N + TOK_BLK - 1) / TOK_BLK;   // 1024
    float* fws = (float*)ws;
    int* idx = (int*)fws;                     // N
    float* counts = fws + N;                  // 512 (accc)
    float* norm = counts + M_CODES;           // 512
    float* lossP = norm + M_CODES;            // nBlk
    float* maskP = lossP + nBlk;              // nBlk
    float* sumE = maskP + nBlk;               // 512
    int* flagCnt = (int*)(sumE + M_CODES);    // 2
    int* flagList = flagCnt + 2;              // N
    float* embT = (float*)(flagList + N);     // 65536
    float* accw = embT + M_CODES * D_EMB;     // 65536

    hipLaunchKernelGGL(kSZ, dim3(M_CODES * D_EMB / 256), dim3(256), 0, stream,
                       emb, sumE, embT, accw, counts, flagCnt);
    hipLaunchKernelGGL(kA, dim3(nBlk), dim3(256), 0, stream, x, xmask, emb,
                       sumE, idx, flagCnt, flagList, lossP, maskP, N);
    hipLaunchKernelGGL(kF, dim3(512), dim3(256), 0, stream, x, xmask, embT, sumE,
                       flagCnt, flagList, idx);
    hipLaunchKernelGGL(kQB, dim3((N * 32 + 255) / 256), dim3(256), 0, stream, x,
                       emb, xmask, idx, q_st, accw, counts, N);
    hipLaunchKernelGGL(kC, dim3(1), dim3(512), 0, stream, counts, ema_count,
                       new_cnt, norm, lossP, maskP, loss, nBlk);
    hipLaunchKernelGGL(kWD, dim3(M_CODES * D_EMB / 256), dim3(256), 0, stream,
                       accw, ema_weight, norm, new_w, new_emb);
}